// Round 5
// baseline (78.437 us; speedup 1.0000x reference)
//
#include <hip/hip_runtime.h>

// out[n,s,a,m] = sum_r x[n,r,a,m] * W[group(a),r,s]
// x: [2048, 12, 20, 128] f32, W: [4, 12, 12] f32, out: [2048, 12, 20, 128] f32
// group(a): sizes [1,3,6,10] -> a=0:g0, 1..3:g1, 4..9:g2, 10..19:g3

#define N_NODES 2048
#define RDIM 12
#define ADIM 20
#define EDIM 128

typedef float f32x4 __attribute__((ext_vector_type(4)));

// One wave handles TWO n-values at the SAME a:
//   lanes 0-31 -> n0, lanes 32-63 -> n0+1, m = (lane&31)*4 (float4).
// 'a' wave-uniform -> g in SGPR -> W via scalar/constant cache.
//
// __launch_bounds__(256, 4): VGPR cap 128/wave. R4's binary showed
// VGPR_Count=32 — too small to hold the 48-VGPR accumulator, meaning the
// compiler was either re-reading x or ping-ponging acc through AGPRs.
// Lifting the cap lets acc[12] (48 VGPR) stay resident across the r-loop:
// each x element is then loaded exactly once, each out written once.
__global__ __launch_bounds__(256, 4) void srlt_kernel(const float* __restrict__ x,
                                                      const float* __restrict__ W,
                                                      float* __restrict__ out) {
    const int wave = threadIdx.x >> 6;   // 4 waves per block
    const int lane = threadIdx.x & 63;
    const int wid = blockIdx.x * 4 + wave;     // wave id over (n/2, a)
    const int npair = wid / ADIM;
    const int a = wid - npair * ADIM;

    int g = (a >= 10) ? 3 : ((a >= 4) ? 2 : ((a >= 1) ? 1 : 0));
    g = __builtin_amdgcn_readfirstlane(g);
    const float* __restrict__ wg = W + g * (RDIM * RDIM);

    const int n = npair * 2 + (lane >> 5);
    const int m = (lane & 31) * 4;

    // flat: ((n*RDIM + r)*ADIM + a)*EDIM + m
    const int base = n * (RDIM * ADIM * EDIM) + a * EDIM + m;
    const f32x4* __restrict__ xp = reinterpret_cast<const f32x4*>(x + base);
    f32x4* __restrict__ op = reinterpret_cast<f32x4*>(out + base);
    const int stride4 = ADIM * EDIM / 4;  // r/s plane stride in float4

    f32x4 acc[RDIM];
#pragma unroll
    for (int s = 0; s < RDIM; ++s) {
        acc[s] = (f32x4)(0.0f);
    }

#pragma unroll
    for (int r = 0; r < RDIM; ++r) {
        const f32x4 xv = xp[r * stride4];
#pragma unroll
        for (int s = 0; s < RDIM; ++s) {
            const float w = wg[r * RDIM + s];  // SGPR operand
            acc[s] = xv * w + acc[s];          // 4x v_fmac_f32
        }
    }

#pragma unroll
    for (int s = 0; s < RDIM; ++s) {
        // streaming store: non-temporal hint (kept from R4; harmless)
        asm volatile("global_store_dwordx4 %0, %1, off nt"
                     :
                     : "v"(op + s * stride4), "v"(acc[s])
                     : "memory");
    }
}

extern "C" void kernel_launch(void* const* d_in, const int* in_sizes, int n_in,
                              void* d_out, int out_size, void* d_ws, size_t ws_size,
                              hipStream_t stream) {
    const float* x = (const float*)d_in[0];
    const float* W = (const float*)d_in[1];
    float* out = (float*)d_out;

    // waves = (N_NODES/2) * ADIM = 20480; 4 waves (256 threads) per block
    const int n_waves = (N_NODES / 2) * ADIM;
    const int grid = n_waves / 4;  // 5120 blocks
    srlt_kernel<<<grid, 256, 0, stream>>>(x, W, out);
}

// Round 6
// 76.816 us; speedup vs baseline: 1.0211x; 1.0211x over previous
//
#include <hip/hip_runtime.h>

// out[n,s,a,m] = sum_r x[n,r,a,m] * W[group(a),r,s]
// x: [2048, 12, 20, 128] f32, W: [4, 12, 12] f32, out: [2048, 12, 20, 128] f32
// group(a): sizes [1,3,6,10] -> a=0:g0, 1..3:g1, 4..9:g2, 10..19:g3

#define N_NODES 2048
#define RDIM 12
#define ADIM 20
#define EDIM 128

typedef float f32x4 __attribute__((ext_vector_type(4)));

// One wave handles TWO n-values at the SAME a:
//   lanes 0-31 -> n0, lanes 32-63 -> n0+1, m = (lane&31)*4 (float4).
// 'a' wave-uniform -> g in SGPR -> W via scalar/constant cache.
//
// KEY LESSON (R4/R5): inline-asm stores with a "memory" clobber inside the
// unrolled loop forced the compiler to reload x after every store (12x read
// amplification through L2, VGPR_Count=32). Structure here guarantees
// load-once: preload all 12 x-vectors into registers BEFORE any store, then
// compute acc[s] one at a time and store immediately (live ~= 48 xv + 4 acc).
__global__ __launch_bounds__(256, 4) void srlt_kernel(const float* __restrict__ x,
                                                      const float* __restrict__ W,
                                                      float* __restrict__ out) {
    const int wave = threadIdx.x >> 6;   // 4 waves per block
    const int lane = threadIdx.x & 63;
    const int wid = blockIdx.x * 4 + wave;     // wave id over (n/2, a)
    const int npair = wid / ADIM;
    const int a = wid - npair * ADIM;

    int g = (a >= 10) ? 3 : ((a >= 4) ? 2 : ((a >= 1) ? 1 : 0));
    g = __builtin_amdgcn_readfirstlane(g);
    const float* __restrict__ wg = W + g * (RDIM * RDIM);

    const int n = npair * 2 + (lane >> 5);
    const int m = (lane & 31) * 4;

    // flat: ((n*RDIM + r)*ADIM + a)*EDIM + m
    const int base = n * (RDIM * ADIM * EDIM) + a * EDIM + m;
    const f32x4* __restrict__ xp = reinterpret_cast<const f32x4*>(x + base);
    f32x4* __restrict__ op = reinterpret_cast<f32x4*>(out + base);
    const int stride4 = ADIM * EDIM / 4;  // r/s plane stride in float4

    // Load ALL of this thread's x slice first: 12 independent dwordx4 loads
    // in flight, then pure compute. 48 VGPRs, guaranteed single read of x.
    f32x4 xv[RDIM];
#pragma unroll
    for (int r = 0; r < RDIM; ++r) {
        xv[r] = xp[r * stride4];
    }

    // s-outer: one accumulator live at a time; store as soon as it's done.
#pragma unroll
    for (int s = 0; s < RDIM; ++s) {
        f32x4 acc = (f32x4)(0.0f);
#pragma unroll
        for (int r = 0; r < RDIM; ++r) {
            acc = xv[r] * wg[r * RDIM + s] + acc;  // w from SGPR
        }
        __builtin_nontemporal_store(acc, &op[s * stride4]);
    }
}

extern "C" void kernel_launch(void* const* d_in, const int* in_sizes, int n_in,
                              void* d_out, int out_size, void* d_ws, size_t ws_size,
                              hipStream_t stream) {
    const float* x = (const float*)d_in[0];
    const float* W = (const float*)d_in[1];
    float* out = (float*)d_out;

    // waves = (N_NODES/2) * ADIM = 20480; 4 waves (256 threads) per block
    const int n_waves = (N_NODES / 2) * ADIM;
    const int grid = n_waves / 4;  // 5120 blocks
    srlt_kernel<<<grid, 256, 0, stream>>>(x, W, out);
}